// Round 6
// baseline (643.119 us; speedup 1.0000x reference)
//
#include <hip/hip_runtime.h>

typedef unsigned short u16;
typedef unsigned int   u32;
typedef _Float16       f16;

#define M_DIM 4096
#define K_DIM 4096
#define N_DIM 11008
#define NQ8   (N_DIM / 8)
#define BM 128
#define BN 128
#define BK 32
#define BKP 40  // Bs k-stride (halfs): 80B rows -> bank stride 20, conflict-free b128 reads

typedef f16   f16x8  __attribute__((ext_vector_type(8)));
typedef f16   f16x2  __attribute__((ext_vector_type(2)));
typedef float f32x16 __attribute__((ext_vector_type(16)));

typedef __attribute__((address_space(1))) void GV;
typedef __attribute__((address_space(3))) void LV;

__device__ __forceinline__ u32 pk2(float lo, float hi) {
    // v_cvt_pkrtz_f16_f32; exact for fp16-representable values (x is fp16-origin).
    return __builtin_bit_cast(u32, __builtin_amdgcn_cvt_pkrtz(lo, hi));
}

// x -> fp16 with per-8-group k-permutation: pairs (k0,k4),(k1,k5),(k2,k6),(k3,k7),
// matching the B-side nibble pairing ((q>>4j)&0x000F000F covers nibbles j and j+4).
__global__ __launch_bounds__(256) void cvt_x(const float* __restrict__ x, f16* __restrict__ xh) {
    const size_t t = (size_t)blockIdx.x * 256 + threadIdx.x;  // one 8-group per thread
    const float4* p = (const float4*)(x + t * 8);
    float4 a0 = p[0], a1 = p[1];
    uint4 v;
    v.x = pk2(a0.x, a1.x); v.y = pk2(a0.y, a1.y);
    v.z = pk2(a0.z, a1.z); v.w = pk2(a0.w, a1.w);
    *(uint4*)(xh + t * 8) = v;
}

// C = x[M,K] @ dequant(qweight)[K,N].  x,scales,out fp32 on device (fp16 promoted).
// W[k,n] = s[g,n]*(w - z - 1), g = k/128.  fp16 32x32x16 MFMA, fp32 accum.
// As layout: [m][k] 128x32 halfs, 16B granule at position p holds global k8-group
// p ^ ((m>>1)&3)  (XOR swizzle -> conflict-free b128 frag reads at 64B row stride).
template<bool PRE>
__global__ __launch_bounds__(256, 2)
void gptq_gemm(const float* __restrict__ x, const f16* __restrict__ xh,
               const int* __restrict__ qw, const float* __restrict__ sc,
               const int* __restrict__ qz, float* __restrict__ out)
{
    __shared__ __align__(16) f16 As[BM * BK];    // 8 KB
    __shared__ __align__(16) f16 Bs[BN * BKP];   // 10 KB

    const int tid  = threadIdx.x;
    const int lane = tid & 63;
    const int wave = tid >> 6;
    const int l31  = lane & 31;
    const int kb   = lane >> 5;         // k-half selector within K=16 frag
    const int wm   = (wave & 1) * 64;
    const int wn   = (wave >> 1) * 64;

    const int m0 = blockIdx.y * BM;
    const int n0 = blockIdx.x * BN;

    // --- A staging (PRE): row m=tid>>2 (+64), LDS granule p=tid&3 holds global
    //     granule p ^ sigma(m), sigma(m)=(m>>1)&3 = (tid>>3)&3 for both halves. ---
    const int swz = ((tid & 3) ^ ((tid >> 3) & 3)) * 8;
    const f16* agh0 = xh + (size_t)(m0 + (tid >> 2)) * K_DIM + swz;
    const f16* agh1 = agh0 + (size_t)64 * K_DIM;
    f16* al0 = As + tid * 8;
    f16* al1 = As + 2048 + tid * 8;

    // --- A staging (!PRE): row m=tid>>1, LDS granules {2h,2h+1}, h=tid&1;
    //     sigma(m) = (tid>>2)&3. ---
    const int fm   = tid >> 1;
    const int fh   = tid & 1;
    const int fsig = (tid >> 2) & 3;
    const float* agf = x + (size_t)(m0 + fm) * K_DIM;
    f16* alf = As + fm * BK;

    // --- B dequant params (fixed n per thread) ---
    const int dn  = tid & 127;
    const int dkq = tid >> 7;    // qweight rows (=granules) dkq and dkq+2 of the k-tile
    const int gn  = n0 + dn;
    const int zsh = (gn & 7) * 4;
    const int*   qwp = qw + gn;
    const int*   qzp = qz + (gn >> 3);
    const float* scp = sc + gn;
    f16* bs0 = Bs + dn * BKP + dkq * 8;

    // --- fragment read pointers (loop-invariant) ---
    const int sigl = (l31 >> 1) & 3;                    // sigma(row), wm-independent
    const f16* pa0 = As + (wm + l31) * BK + ((0 + kb) ^ sigl) * 8;  // ks=0
    const f16* pa1 = As + (wm + l31) * BK + ((2 + kb) ^ sigl) * 8;  // ks=1
    const f16* pb  = Bs + (wn + l31) * BKP + kb * 8;

    f32x16 acc[2][2];
    #pragma unroll
    for (int i = 0; i < 2; i++)
        #pragma unroll
        for (int j = 0; j < 2; j++)
            acc[i][j] = (f32x16)(0.f);

    for (int g = 0; g < K_DIM / 128; g++) {        // 32 quant groups
        const u32 zq = (u32)qzp[(size_t)g * NQ8];
        const int z1 = (int)((zq >> zsh) & 15u) + 1;
        const float s = scp[(size_t)g * N_DIM];
        const f16 sh = (f16)s;
        const f16 bh = (f16)(-(float)(1024 + z1));  // exact integer in fp16
        const f16x2 s2 = {sh, sh};
        const f16x2 b2 = {bh, bh};

        #pragma unroll
        for (int t = 0; t < 4; t++) {
            const int kt = g * 4 + t;

            if constexpr (PRE) {
                __builtin_amdgcn_global_load_lds((GV*)(agh0 + kt * BK), (LV*)al0, 16, 0, 0);
                __builtin_amdgcn_global_load_lds((GV*)(agh1 + kt * BK), (LV*)al1, 16, 0, 0);
            } else {
                #pragma unroll
                for (int e = 0; e < 2; e++) {
                    const int p = 2 * fh + e;
                    const float4* src = (const float4*)(agf + kt * BK + ((p ^ fsig) * 8));
                    float4 a0 = src[0], a1 = src[1];
                    uint4 v;  // pairing permutation (k0,k4)...
                    v.x = pk2(a0.x, a1.x); v.y = pk2(a0.y, a1.y);
                    v.z = pk2(a0.z, a1.z); v.w = pk2(a0.w, a1.w);
                    *(uint4*)(alf + p * 8) = v;
                }
            }

            // B: dequant 2 dwords (16 k-values) for this thread's n
            uint4 bv[2];
            #pragma unroll
            for (int i = 0; i < 2; i++) {
                const u32 q = (u32)qwp[(size_t)(4 * kt + dkq + 2 * i) * N_DIM];
                u32 pk[4];
                #pragma unroll
                for (int j = 0; j < 4; j++) {
                    const u32 mbits = ((q >> (4 * j)) & 0x000F000Fu) | 0x64006400u;
                    f16x2 v2 = __builtin_bit_cast(f16x2, mbits);
                    f16x2 w2 = (v2 + b2) * s2;      // exact add, single-rounded mul
                    pk[j] = __builtin_bit_cast(u32, w2);
                }
                bv[i].x = pk[0]; bv[i].y = pk[1]; bv[i].z = pk[2]; bv[i].w = pk[3];
            }
            *(uint4*)(bs0)      = bv[0];   // granule dkq
            *(uint4*)(bs0 + 16) = bv[1];   // granule dkq+2
            __syncthreads();

            // fragments: af[mt][ks], bf[nt][ks]
            f16x8 af[2][2], bf[2][2];
            #pragma unroll
            for (int mt = 0; mt < 2; mt++) {
                af[mt][0] = *(const f16x8*)(pa0 + mt * 32 * BK);
                af[mt][1] = *(const f16x8*)(pa1 + mt * 32 * BK);
            }
            #pragma unroll
            for (int nt = 0; nt < 2; nt++) {
                bf[nt][0] = *(const f16x8*)(pb + nt * 32 * BKP);
                bf[nt][1] = *(const f16x8*)(pb + nt * 32 * BKP + 16);
            }
            #pragma unroll
            for (int mt = 0; mt < 2; mt++)
                #pragma unroll
                for (int nt = 0; nt < 2; nt++)
                    #pragma unroll
                    for (int ks = 0; ks < 2; ks++)
                        acc[mt][nt] = __builtin_amdgcn_mfma_f32_32x32x16_f16(
                            af[mt][ks], bf[nt][ks], acc[mt][nt], 0, 0, 0);
            __syncthreads();
        }
    }

    // epilogue: C/D col=lane&31, row=(reg&3)+8*(reg>>2)+4*(lane>>5)  [m74/m101]
    #pragma unroll
    for (int mt = 0; mt < 2; mt++)
        #pragma unroll
        for (int nt = 0; nt < 2; nt++) {
            const int ncol = n0 + wn + nt * 32 + l31;
            #pragma unroll
            for (int r = 0; r < 16; r++) {
                const int mrow = m0 + wm + mt * 32 + (r & 3) + 8 * (r >> 2) + 4 * kb;
                out[(size_t)mrow * N_DIM + ncol] = acc[mt][nt][r];
            }
        }
}

extern "C" void kernel_launch(void* const* d_in, const int* in_sizes, int n_in,
                              void* d_out, int out_size, void* d_ws, size_t ws_size,
                              hipStream_t stream) {
    const float* x  = (const float*)d_in[0];
    const int*   qw = (const int*)d_in[1];
    const float* sc = (const float*)d_in[2];
    const int*   qz = (const int*)d_in[3];
    float* out = (float*)d_out;
    f16*   xh  = (f16*)d_ws;

    dim3 grid(N_DIM / BN, M_DIM / BM);  // (86, 32)
    const bool pre = ws_size >= (size_t)M_DIM * K_DIM * sizeof(f16);  // 32 MB
    if (pre) {
        cvt_x<<<(M_DIM * K_DIM / 8) / 256, 256, 0, stream>>>(x, xh);
        gptq_gemm<true><<<grid, 256, 0, stream>>>(x, xh, qw, sc, qz, out);
    } else {
        gptq_gemm<false><<<grid, 256, 0, stream>>>(x, xh, qw, sc, qz, out);
    }
}